// Round 8
// baseline (108.927 us; speedup 1.0000x reference)
//
#include <hip/hip_runtime.h>

#define NQ 6
#define DIM 64
#define NL 8

#define WP  72    // W f16 row pitch (144 B rows, 16B-aligned)

typedef __attribute__((ext_vector_type(4))) float    floatx4;
typedef __attribute__((ext_vector_type(4))) _Float16 half4v;   // 4 f16 = 2 VGPRs

// ---------------------------------------------------------------------------
// Prep (circuit verified rounds 1-7): build unitary U, emit to ws:
//   Wf[128][WP] f16 : rows n<64 = Re(U)[n][*], n>=64 = Im(U)[n-64][*]
//   M5h table (f16) at byte offset 128*WP*2: A-fragment-ready for
//   mfma_f32_16x16x16f16: entry [c2][lane][j] = M5[c2*16+(lane>>4)*4+j][lane&15]
//   where M5[i][c<4] = sum_q sign(i,q) fc_w[c][q], M5[i][4] = 1, else 0.
// ---------------------------------------------------------------------------
__global__ __launch_bounds__(64) void qnn_prep(
    const float* __restrict__ wts,   // [8*6*3] (phi, theta, omega)
    const float* __restrict__ fc_w,  // [4*6]
    void* __restrict__ ws)
{
    __shared__ float gc[48][4];
    const int n   = threadIdx.x;     // amplitude row 0..63
    const int col = blockIdx.x;      // basis column 0..63

    if (n < 48) {
        float phi = wts[n*3+0], th = wts[n*3+1], om = wts[n*3+2];
        float ch = cosf(0.5f*th), sh = sinf(0.5f*th);
        float p  = 0.5f*(phi+om), m  = 0.5f*(phi-om);
        gc[n][0] = cosf(p)*ch;
        gc[n][1] = sinf(p)*ch;
        gc[n][2] = cosf(m)*sh;
        gc[n][3] = sinf(m)*sh;
    }
    __syncthreads();

    float ar = (n == col) ? 1.0f : 0.0f;
    float ai = 0.0f;

    #pragma unroll
    for (int l = 0; l < NL; ++l) {
        #pragma unroll
        for (int q = 0; q < NQ; ++q) {
            const int g     = l*NQ + q;
            const int shift = 5 - q;
            const int mask  = 1 << shift;
            const int b     = (n >> shift) & 1;
            const float cpch = gc[g][0];
            const float spch = gc[g][1];
            const float cmsh = gc[g][2];
            const float smsh = gc[g][3];
            const float pr = __shfl_xor(ar, mask, 64);
            const float pi = __shfl_xor(ai, mask, 64);
            const float udr = cpch;
            const float udi = b ?  spch : -spch;
            const float uor = b ?  cmsh : -cmsh;
            const float uoi = -smsh;
            const float nr = udr*ar - udi*ai + uor*pr - uoi*pi;
            const float ni = udr*ai + udi*ar + uor*pi + uoi*pr;
            ar = nr; ai = ni;
        }
        const int r = (l % (NQ - 1)) + 1;
        #pragma unroll
        for (int q = 0; q < NQ; ++q) {
            const int t     = (q + r) % NQ;
            const int cmask = 1 << (5 - q);
            const int tmask = 1 << (5 - t);
            const float pr = __shfl_xor(ar, tmask, 64);
            const float pi = __shfl_xor(ai, tmask, 64);
            const bool ctrl = (n & cmask) != 0;
            ar = ctrl ? pr : ar;
            ai = ctrl ? pi : ai;
        }
    }

    _Float16* Wf = (_Float16*)ws;
    Wf[n*WP + col]      = (_Float16)ar;
    Wf[(64+n)*WP + col] = (_Float16)ai;

    if (col == 0) {
        const int cp = n & 15;            // c' = l15
        const int qd = n >> 4;            // quad
        half4v* Mo = (half4v*)((char*)ws + 128*WP*2);
        #pragma unroll
        for (int c2 = 0; c2 < 4; ++c2) {
            half4v h4;
            #pragma unroll
            for (int j = 0; j < 4; ++j) {
                const int i = c2*16 + qd*4 + j;
                float v = 0.f;
                if (cp < 4) {
                    #pragma unroll
                    for (int q = 0; q < NQ; ++q) {
                        const float sgn = 1.0f - 2.0f*(float)((i >> (5-q)) & 1);
                        v = fmaf(sgn, fc_w[cp*NQ + q], v);
                    }
                } else if (cp == 4) {
                    v = 1.0f;             // ones column -> ss
                }
                h4[j] = (_Float16)v;
            }
            Mo[c2*64 + n] = h4;
        }
    }
}

// ---------------------------------------------------------------------------
// Main: occupancy-first. 2048 blocks x 256 thr, __launch_bounds__(256,4)
// -> 16 waves/CU (2x rounds 4-7). W f16 in LDS (18.4 KB/block), fragments
// re-read per tile via ds_read_b64; x via 4 direct float4 loads per
// 16-sample tile (both tiles issued up-front); fp32 MFMA accumulate;
// f16-MFMA epilogue; shfl_xor(16) for ss; float4 store from quad-0 lanes.
// Register budget ~95 VGPR so 4 waves/EU actually materialize.
// ---------------------------------------------------------------------------
__global__ __launch_bounds__(256, 4) void qnn_main(
    const float* __restrict__ x,
    const float* __restrict__ fc_b,
    const void* __restrict__ wsv,
    float* __restrict__ out)
{
    __shared__ __align__(16) _Float16 Ws[128*WP];   // 18432 B

    const int tid  = threadIdx.x;
    const int lane = tid & 63;
    const int w    = tid >> 6;
    const int l15  = lane & 15;
    const int quad = lane >> 4;
    const size_t gw = (size_t)blockIdx.x*4 + w;     // global wave 0..8191

    // --- issue x loads for both 16-sample tiles first (8 loads in flight) ---
    // xr[t][kc] = x[sample = gw*32 + t*16 + l15][k = kc*16 + quad*4 .. +3]
    float4 xr[2][4];
    #pragma unroll
    for (int t = 0; t < 2; ++t) {
        const float* xp = x + (gw*32 + (size_t)t*16 + l15)*DIM + quad*4;
        #pragma unroll
        for (int kc = 0; kc < 4; ++kc)
            xr[t][kc] = *(const float4*)(xp + kc*16);
    }

    // --- stage W into LDS (1152 float4s, 256 threads x 5 rounds) ---
    {
        const floatx4* wg = (const floatx4*)wsv;
        floatx4* wl = (floatx4*)Ws;
        #pragma unroll
        for (int i = 0; i < 5; ++i) {
            const int idx = tid + i*256;
            if (idx < 128*WP*2/16) wl[idx] = wg[idx];
        }
    }

    // --- M5 epilogue A-fragments + bias ---
    const half4v* Mg = (const half4v*)((const char*)wsv + 128*WP*2);
    half4v a2[4];
    #pragma unroll
    for (int c2 = 0; c2 < 4; ++c2) a2[c2] = Mg[c2*64 + lane];
    const float b0 = fc_b[0], b1 = fc_b[1], b2 = fc_b[2], b3 = fc_b[3];

    __syncthreads();   // Ws ready

    #pragma unroll
    for (int t = 0; t < 2; ++t) {
        // convert this tile's x to f16 B-fragments
        half4v xf[4];
        #pragma unroll
        for (int kc = 0; kc < 4; ++kc) {
            const float4 u = xr[t][kc];
            half4v h;
            h[0] = (_Float16)u.x; h[1] = (_Float16)u.y;
            h[2] = (_Float16)u.z; h[3] = (_Float16)u.w;
            xf[kc] = h;
        }

        // K=64 GEMM: A = W rows (LDS fragments), B = x
        floatx4 acc[8];
        #pragma unroll
        for (int mt = 0; mt < 8; ++mt) acc[mt] = (floatx4){0.f, 0.f, 0.f, 0.f};

        #pragma unroll
        for (int kc = 0; kc < 4; ++kc) {
            #pragma unroll
            for (int mt = 0; mt < 8; ++mt) {
                const half4v wf = *(const half4v*)
                    &Ws[(mt*16 + l15)*WP + kc*16 + quad*4];
                acc[mt] = __builtin_amdgcn_mfma_f32_16x16x16f16(
                    wf, xf[kc], acc[mt], 0, 0, 0);
            }
        }

        // epilogue: out[c][s] = sum_i M5[i][c] * p[i][s] via f16 MFMA
        floatx4 d2 = (floatx4){0.f, 0.f, 0.f, 0.f};
        #pragma unroll
        for (int c2 = 0; c2 < 4; ++c2) {
            half4v pb;
            #pragma unroll
            for (int r = 0; r < 4; ++r) {
                const float re = acc[c2][r];
                const float im = acc[c2 + 4][r];
                pb[r] = (_Float16)fmaf(re, re, im*im);
            }
            d2 = __builtin_amdgcn_mfma_f32_16x16x16f16(a2[c2], pb, d2, 0, 0, 0);
        }
        // d2 reg r = D2[row=quad*4+r][col=l15]; rows 0..3 = logits, row 4 = ss
        const float ssv = __shfl_xor(d2[0], 16, 64);
        if (quad == 0) {
            const float inv = 1.0f / ssv;
            float4 o;
            o.x = fmaf(d2[0], inv, b0);
            o.y = fmaf(d2[1], inv, b1);
            o.z = fmaf(d2[2], inv, b2);
            o.w = fmaf(d2[3], inv, b3);
            *(float4*)(out + (gw*32 + (size_t)t*16 + l15)*4) = o;
        }
    }
}

extern "C" void kernel_launch(void* const* d_in, const int* in_sizes, int n_in,
                              void* d_out, int out_size, void* d_ws, size_t ws_size,
                              hipStream_t stream) {
    const float* x    = (const float*)d_in[0];   // [262144, 64]
    const float* wts  = (const float*)d_in[1];   // [8, 6, 3]
    const float* fc_w = (const float*)d_in[2];   // [4, 6]
    const float* fc_b = (const float*)d_in[3];   // [4]
    float* out = (float*)d_out;                  // [262144, 4]

    // 2048 blocks x 4 waves x 2 tiles x 16 samples = 262144
    qnn_prep<<<DIM, DIM, 0, stream>>>(wts, fc_w, d_ws);
    qnn_main<<<2048, 256, 0, stream>>>(x, fc_b, d_ws, out);
}

// Round 9
// 107.294 us; speedup vs baseline: 1.0152x; 1.0152x over previous
//
#include <hip/hip_runtime.h>

#define NQ 6
#define DIM 64
#define NL 8

#define WP  72    // W f16 row pitch (144 B rows, 16B-aligned)

typedef __attribute__((ext_vector_type(4))) float    floatx4;
typedef __attribute__((ext_vector_type(4))) _Float16 half4v;   // 4 f16 = 2 VGPRs
typedef __attribute__((ext_vector_type(8))) _Float16 half8v;   // 8 f16 = 4 VGPRs

// ---------------------------------------------------------------------------
// Prep (circuit verified rounds 1-8): build unitary U, emit to ws:
//   Wf[128][WP] f16 : rows n<64 = Re(U)[n][*], n>=64 = Im(U)[n-64][*]
//   M5h table (f16) at byte offset 128*WP*2: A-fragment-ready for
//   mfma_f32_16x16x16f16: entry [c2][lane][j] = M5[c2*16+(lane>>4)*4+j][lane&15]
//   where M5[i][c<4] = sum_q sign(i,q) fc_w[c][q], M5[i][4] = 1, else 0.
// ---------------------------------------------------------------------------
__global__ __launch_bounds__(64) void qnn_prep(
    const float* __restrict__ wts,   // [8*6*3] (phi, theta, omega)
    const float* __restrict__ fc_w,  // [4*6]
    void* __restrict__ ws)
{
    __shared__ float gc[48][4];
    const int n   = threadIdx.x;     // amplitude row 0..63
    const int col = blockIdx.x;      // basis column 0..63

    if (n < 48) {
        float phi = wts[n*3+0], th = wts[n*3+1], om = wts[n*3+2];
        float ch = cosf(0.5f*th), sh = sinf(0.5f*th);
        float p  = 0.5f*(phi+om), m  = 0.5f*(phi-om);
        gc[n][0] = cosf(p)*ch;
        gc[n][1] = sinf(p)*ch;
        gc[n][2] = cosf(m)*sh;
        gc[n][3] = sinf(m)*sh;
    }
    __syncthreads();

    float ar = (n == col) ? 1.0f : 0.0f;
    float ai = 0.0f;

    #pragma unroll
    for (int l = 0; l < NL; ++l) {
        #pragma unroll
        for (int q = 0; q < NQ; ++q) {
            const int g     = l*NQ + q;
            const int shift = 5 - q;
            const int mask  = 1 << shift;
            const int b     = (n >> shift) & 1;
            const float cpch = gc[g][0];
            const float spch = gc[g][1];
            const float cmsh = gc[g][2];
            const float smsh = gc[g][3];
            const float pr = __shfl_xor(ar, mask, 64);
            const float pi = __shfl_xor(ai, mask, 64);
            const float udr = cpch;
            const float udi = b ?  spch : -spch;
            const float uor = b ?  cmsh : -cmsh;
            const float uoi = -smsh;
            const float nr = udr*ar - udi*ai + uor*pr - uoi*pi;
            const float ni = udr*ai + udi*ar + uor*pi + uoi*pr;
            ar = nr; ai = ni;
        }
        const int r = (l % (NQ - 1)) + 1;
        #pragma unroll
        for (int q = 0; q < NQ; ++q) {
            const int t     = (q + r) % NQ;
            const int cmask = 1 << (5 - q);
            const int tmask = 1 << (5 - t);
            const float pr = __shfl_xor(ar, tmask, 64);
            const float pi = __shfl_xor(ai, tmask, 64);
            const bool ctrl = (n & cmask) != 0;
            ar = ctrl ? pr : ar;
            ai = ctrl ? pi : ai;
        }
    }

    _Float16* Wf = (_Float16*)ws;
    Wf[n*WP + col]      = (_Float16)ar;
    Wf[(64+n)*WP + col] = (_Float16)ai;

    if (col == 0) {
        const int cp = n & 15;            // c' = l15
        const int qd = n >> 4;            // quad
        half4v* Mo = (half4v*)((char*)ws + 128*WP*2);
        #pragma unroll
        for (int c2 = 0; c2 < 4; ++c2) {
            half4v h4;
            #pragma unroll
            for (int j = 0; j < 4; ++j) {
                const int i = c2*16 + qd*4 + j;
                float v = 0.f;
                if (cp < 4) {
                    #pragma unroll
                    for (int q = 0; q < NQ; ++q) {
                        const float sgn = 1.0f - 2.0f*(float)((i >> (5-q)) & 1);
                        v = fmaf(sgn, fc_w[cp*NQ + q], v);
                    }
                } else if (cp == 4) {
                    v = 1.0f;             // ones column -> ss
                }
                h4[j] = (_Float16)v;
            }
            Mo[c2*64 + n] = h4;
        }
    }
}

// ---------------------------------------------------------------------------
// Main: ZERO LDS, zero barriers, zero DS instructions. 2048 blocks x 256 thr,
// __launch_bounds__(256,3) -> 12 waves/CU. Each wave keeps all of W in
// registers as 16 f16 A-fragments (64 VGPRs, 16x16x32_f16 layout:
// wfr[kk][mt] = W[mt*16+l15][kk*32+quad*8 .. +7]) + M5 epilogue fragments.
// Per 16-sample tile (2 tiles/wave, all x loads issued up-front):
// 4 float4 x-loads -> f16 convert -> 16x mfma_f32_16x16x32_f16 ->
// f16-MFMA epilogue -> shfl_xor(16) for ss -> float4 store (quad-0 lanes).
// ---------------------------------------------------------------------------
__global__ __launch_bounds__(256, 3) void qnn_main(
    const float* __restrict__ x,
    const float* __restrict__ fc_b,
    const void* __restrict__ wsv,
    float* __restrict__ out)
{
    const int tid  = threadIdx.x;
    const int lane = tid & 63;
    const int w    = tid >> 6;
    const int l15  = lane & 15;
    const int quad = lane >> 4;
    const size_t gw = (size_t)blockIdx.x*4 + w;     // global wave 0..8191

    // --- x loads for both 16-sample tiles, issued first (8 in flight) ---
    // tile t, fragment kk: x[sample = gw*32 + t*16 + l15][kk*32 + quad*8 ..+7]
    float4 xr[2][2][2];   // [t][kk][pair]
    #pragma unroll
    for (int t = 0; t < 2; ++t) {
        const float* xp = x + (gw*32 + (size_t)t*16 + l15)*DIM + quad*8;
        #pragma unroll
        for (int kk = 0; kk < 2; ++kk) {
            xr[t][kk][0] = *(const float4*)(xp + kk*32);
            xr[t][kk][1] = *(const float4*)(xp + kk*32 + 4);
        }
    }

    // --- W fragments into registers (L2-hot broadcast read) ---
    const _Float16* Wf = (const _Float16*)wsv;
    half8v wfr[2][8];
    #pragma unroll
    for (int kk = 0; kk < 2; ++kk)
        #pragma unroll
        for (int mt = 0; mt < 8; ++mt)
            wfr[kk][mt] = *(const half8v*)(Wf + (mt*16 + l15)*WP + kk*32 + quad*8);

    // --- M5 epilogue A-fragments + bias ---
    const half4v* Mg = (const half4v*)((const char*)wsv + 128*WP*2);
    half4v a2[4];
    #pragma unroll
    for (int c2 = 0; c2 < 4; ++c2) a2[c2] = Mg[c2*64 + lane];
    const float b0 = fc_b[0], b1 = fc_b[1], b2 = fc_b[2], b3 = fc_b[3];

    #pragma unroll
    for (int t = 0; t < 2; ++t) {
        // convert this tile's x to f16 B-fragments (B[k=quad*8+j][n=l15])
        half8v xf[2];
        #pragma unroll
        for (int kk = 0; kk < 2; ++kk) {
            const float4 u0 = xr[t][kk][0];
            const float4 u1 = xr[t][kk][1];
            half8v h;
            h[0] = (_Float16)u0.x; h[1] = (_Float16)u0.y;
            h[2] = (_Float16)u0.z; h[3] = (_Float16)u0.w;
            h[4] = (_Float16)u1.x; h[5] = (_Float16)u1.y;
            h[6] = (_Float16)u1.z; h[7] = (_Float16)u1.w;
            xf[kk] = h;
        }

        // K=64 GEMM: A = W (registers), B = x (registers)
        floatx4 acc[8];
        #pragma unroll
        for (int mt = 0; mt < 8; ++mt) acc[mt] = (floatx4){0.f, 0.f, 0.f, 0.f};
        #pragma unroll
        for (int kk = 0; kk < 2; ++kk)
            #pragma unroll
            for (int mt = 0; mt < 8; ++mt)
                acc[mt] = __builtin_amdgcn_mfma_f32_16x16x32_f16(
                    wfr[kk][mt], xf[kk], acc[mt], 0, 0, 0);

        // epilogue: out[c][s] = sum_i M5[i][c] * p[i][s] via f16 MFMA
        floatx4 d2 = (floatx4){0.f, 0.f, 0.f, 0.f};
        #pragma unroll
        for (int c2 = 0; c2 < 4; ++c2) {
            half4v pb;
            #pragma unroll
            for (int r = 0; r < 4; ++r) {
                const float re = acc[c2][r];
                const float im = acc[c2 + 4][r];
                pb[r] = (_Float16)fmaf(re, re, im*im);
            }
            d2 = __builtin_amdgcn_mfma_f32_16x16x16f16(a2[c2], pb, d2, 0, 0, 0);
        }
        // d2 reg r = D2[row=quad*4+r][col=l15]; rows 0..3 = logits, row 4 = ss
        const float ssv = __shfl_xor(d2[0], 16, 64);
        if (quad == 0) {
            const float inv = 1.0f / ssv;
            float4 o;
            o.x = fmaf(d2[0], inv, b0);
            o.y = fmaf(d2[1], inv, b1);
            o.z = fmaf(d2[2], inv, b2);
            o.w = fmaf(d2[3], inv, b3);
            *(float4*)(out + (gw*32 + (size_t)t*16 + l15)*4) = o;
        }
    }
}

extern "C" void kernel_launch(void* const* d_in, const int* in_sizes, int n_in,
                              void* d_out, int out_size, void* d_ws, size_t ws_size,
                              hipStream_t stream) {
    const float* x    = (const float*)d_in[0];   // [262144, 64]
    const float* wts  = (const float*)d_in[1];   // [8, 6, 3]
    const float* fc_w = (const float*)d_in[2];   // [4, 6]
    const float* fc_b = (const float*)d_in[3];   // [4]
    float* out = (float*)d_out;                  // [262144, 4]

    // 2048 blocks x 4 waves x 2 tiles x 16 samples = 262144
    qnn_prep<<<DIM, DIM, 0, stream>>>(wts, fc_w, d_ws);
    qnn_main<<<2048, 256, 0, stream>>>(x, fc_b, d_ws, out);
}